// Round 1
// baseline (1556.396 us; speedup 1.0000x reference)
//
#include <hip/hip_runtime.h>
#include <math.h>

typedef float f32x4 __attribute__((ext_vector_type(4)));
typedef float f32x2 __attribute__((ext_vector_type(2)));
typedef int   i32x4 __attribute__((ext_vector_type(4)));

// One fused kernel.
// Phase A: pairwise mean over x rows (D=128): out row s = 0.5*(row 2s + row 2s+1).
//          Grid-stride over S*32 float4 outputs, non-temporal (data is single-use).
// Phase B: pos mean / ori mean+normalize / seq max>>1 / batch max.
//          One thread per PAIR of segments so all loads are 16B-aligned vectors
//          and all stores are 8B-aligned float2.
__global__ __launch_bounds__(256) void fused_pool_kernel(
    const f32x4* __restrict__ x4,
    f32x4*       __restrict__ xo4,
    const float* __restrict__ pos,
    const int*   __restrict__ seq,
    const float* __restrict__ ori,
    const int*   __restrict__ batch,
    float* __restrict__ pos_out,
    float* __restrict__ seq_out,
    float* __restrict__ ori_out,
    float* __restrict__ batch_out,
    long total4, int S)
{
    const long nth = (long)gridDim.x * blockDim.x;
    const long tid = (long)blockIdx.x * blockDim.x + threadIdx.x;

    // ---------- Phase A: x (1.5 GiB of the 1.7 GB total traffic) ----------
    #pragma unroll 4
    for (long i = tid; i < total4; i += nth) {
        const long seg = i >> 5;          // output row
        const long j   = i & 31;          // float4 within row
        const f32x4* pa = &x4[seg * 64 + j];
        f32x4 a = __builtin_nontemporal_load(pa);        // row 2*seg
        f32x4 b = __builtin_nontemporal_load(pa + 32);   // row 2*seg+1
        f32x4 o = (a + b) * 0.5f;
        __builtin_nontemporal_store(o, &xo4[i]);
    }

    // ---------- Phase B: misc, one thread per 2 segments ----------
    const long pairs = (long)S >> 1;
    for (long t = tid; t < pairs; t += nth) {
        // ---- pos: 12 floats = 3 aligned float4 ----
        {
            const f32x4* p4 = (const f32x4*)(pos + 12 * t);
            f32x4 p0 = __builtin_nontemporal_load(p4 + 0);
            f32x4 p1 = __builtin_nontemporal_load(p4 + 1);
            f32x4 p2 = __builtin_nontemporal_load(p4 + 2);
            f32x2 w0, w1, w2;
            w0.x = (p0.x + p0.w) * 0.5f;   // seg a = 2t
            w0.y = (p0.y + p1.x) * 0.5f;
            w1.x = (p0.z + p1.y) * 0.5f;
            w1.y = (p1.z + p2.y) * 0.5f;   // seg b = 2t+1
            w2.x = (p1.w + p2.z) * 0.5f;
            w2.y = (p2.x + p2.w) * 0.5f;
            f32x2* po2 = (f32x2*)(pos_out + 6 * t);      // 8B-aligned (6t even)
            __builtin_nontemporal_store(w0, po2 + 0);
            __builtin_nontemporal_store(w1, po2 + 1);
            __builtin_nontemporal_store(w2, po2 + 2);
        }
        // ---- ori: mean then L2-normalize (clamped like the reference) ----
        {
            const f32x4* o4 = (const f32x4*)(ori + 12 * t);
            f32x4 q0 = __builtin_nontemporal_load(o4 + 0);
            f32x4 q1 = __builtin_nontemporal_load(o4 + 1);
            f32x4 q2 = __builtin_nontemporal_load(o4 + 2);
            float oax = (q0.x + q0.w) * 0.5f;
            float oay = (q0.y + q1.x) * 0.5f;
            float oaz = (q0.z + q1.y) * 0.5f;
            float obx = (q1.z + q2.y) * 0.5f;
            float oby = (q1.w + q2.z) * 0.5f;
            float obz = (q2.x + q2.w) * 0.5f;
            float ia = 1.0f / fmaxf(sqrtf(oax*oax + oay*oay + oaz*oaz), 1e-12f);
            float ib = 1.0f / fmaxf(sqrtf(obx*obx + oby*oby + obz*obz), 1e-12f);
            f32x2 w0, w1, w2;
            w0.x = oax * ia; w0.y = oay * ia;
            w1.x = oaz * ia; w1.y = obx * ib;
            w2.x = oby * ib; w2.y = obz * ib;
            f32x2* oo2 = (f32x2*)(ori_out + 6 * t);
            __builtin_nontemporal_store(w0, oo2 + 0);
            __builtin_nontemporal_store(w1, oo2 + 1);
            __builtin_nontemporal_store(w2, oo2 + 2);
        }
        // ---- seq: max(seq>>1) per pair; batch: max per pair ----
        {
            i32x4 sq = __builtin_nontemporal_load((const i32x4*)(seq + 4 * t));
            int sa0 = sq.x >> 1, sa1 = sq.y >> 1;
            int sb0 = sq.z >> 1, sb1 = sq.w >> 1;
            f32x2 sw;
            sw.x = (float)(sa0 > sa1 ? sa0 : sa1);
            sw.y = (float)(sb0 > sb1 ? sb0 : sb1);
            __builtin_nontemporal_store(sw, (f32x2*)(seq_out + 2 * t));

            i32x4 bq = __builtin_nontemporal_load((const i32x4*)(batch + 4 * t));
            f32x2 bw;
            bw.x = (float)(bq.x > bq.y ? bq.x : bq.y);
            bw.y = (float)(bq.z > bq.w ? bq.z : bq.w);
            __builtin_nontemporal_store(bw, (f32x2*)(batch_out + 2 * t));
        }
    }

    // ---- odd-S tail (not exercised at N=2M; kept for generality) ----
    if ((S & 1) && tid == 0) {
        int s = S - 1;
        long p0i = (long)(2 * s) * 3;
        long o3  = (long)s * 3;
        pos_out[o3 + 0] = (pos[p0i + 0] + pos[p0i + 3]) * 0.5f;
        pos_out[o3 + 1] = (pos[p0i + 1] + pos[p0i + 4]) * 0.5f;
        pos_out[o3 + 2] = (pos[p0i + 2] + pos[p0i + 5]) * 0.5f;
        float ox = (ori[p0i + 0] + ori[p0i + 3]) * 0.5f;
        float oy = (ori[p0i + 1] + ori[p0i + 4]) * 0.5f;
        float oz = (ori[p0i + 2] + ori[p0i + 5]) * 0.5f;
        float inv = 1.0f / fmaxf(sqrtf(ox*ox + oy*oy + oz*oz), 1e-12f);
        ori_out[o3 + 0] = ox * inv;
        ori_out[o3 + 1] = oy * inv;
        ori_out[o3 + 2] = oz * inv;
        int s0 = seq[2 * s] >> 1, s1 = seq[2 * s + 1] >> 1;
        seq_out[s] = (float)(s0 > s1 ? s0 : s1);
        int b0 = batch[2 * s], b1 = batch[2 * s + 1];
        batch_out[s] = (float)(b0 > b1 ? b0 : b1);
    }
}

extern "C" void kernel_launch(void* const* d_in, const int* in_sizes, int n_in,
                              void* d_out, int out_size, void* d_ws, size_t ws_size,
                              hipStream_t stream) {
    const float* x     = (const float*)d_in[0];
    const float* pos   = (const float*)d_in[1];
    const int*   seq   = (const int*)d_in[2];
    const float* ori   = (const float*)d_in[3];
    const int*   batch = (const int*)d_in[4];

    const int N = in_sizes[2];   // seq element count
    const int S = N / 2;         // segments (consecutive pairs)

    float* out       = (float*)d_out;
    float* x_out     = out;                        // S*128
    float* pos_out   = out + (size_t)S * 128;      // S*3
    float* seq_out   = out + (size_t)S * 131;      // S*1
    float* ori_out   = out + (size_t)S * 132;      // S*3
    float* batch_out = out + (size_t)S * 135;      // S*1

    const long total4 = (long)S * 32;   // float4 count for x output

    // 2048 blocks x 256 threads = 8 blocks/CU x 4 waves = 32 waves/CU (full
    // occupancy), grid-stride covers the rest (G11).
    const int block = 256;
    const int grid  = 2048;
    fused_pool_kernel<<<dim3(grid), dim3(block), 0, stream>>>(
        (const f32x4*)x, (f32x4*)x_out, pos, seq, ori, batch,
        pos_out, seq_out, ori_out, batch_out, total4, S);
}